// Round 4
// baseline (443.279 us; speedup 1.0000x reference)
//
#include <hip/hip_runtime.h>
#include <hip/hip_bf16.h>
#include <math.h>

// GCN 2-layer forward, bucket-partitioned.
// Round-4 structure: aggregation accumulates RAW pre-scaled-by-src values
// (dinv[dst] applied once at merge), gather table in bf16 (3.2MB -> L2-resident),
// 8x unrolled independent packed->gather chains, padded LDS accumulator.

#define F_IN 128
#define H1 16
#define C_OUT 2
#define NPB 128        // nodes per bucket (dst >> 7)
#define LOG_NPB 7
#define CH 4096        // edges per partition chunk
#define K_MAX 1024     // max buckets / chunks supported

__device__ __forceinline__ float bflo(unsigned u) { return __uint_as_float(u << 16); }
__device__ __forceinline__ float bfhi(unsigned u) { return __uint_as_float(u & 0xFFFF0000u); }

// ---- pass A: per-chunk histogram of dst buckets; cnt layout [K][nblk] ----
__global__ __launch_bounds__(256) void k_part_count(
    const int* __restrict__ dst0, int* __restrict__ cnt, int E, int K, int nblk) {
    __shared__ int sc[K_MAX];
    for (int i = threadIdx.x; i < K; i += 256) sc[i] = 0;
    __syncthreads();
    int e0 = blockIdx.x * CH, e1 = min(e0 + CH, E);
    for (int e = e0 + threadIdx.x; e < e1; e += 256)
        atomicAdd(&sc[((unsigned)dst0[e]) >> LOG_NPB], 1);
    __syncthreads();
    for (int b = threadIdx.x; b < K; b += 256)
        cnt[(size_t)b * nblk + blockIdx.x] = sc[b];
}

// ---- pass B1: per-bucket exclusive scan over chunks (block per bucket) ----
__global__ __launch_bounds__(1024) void k_colscan(
    int* __restrict__ cnt, int* __restrict__ tot, int nblk) {
    __shared__ int s[K_MAX];
    int t = threadIdx.x;
    int* row = cnt + (size_t)blockIdx.x * nblk;
    int own = (t < nblk) ? row[t] : 0;
    s[t] = own;
    __syncthreads();
    for (int off = 1; off < K_MAX; off <<= 1) {
        int v = (t >= off) ? s[t - off] : 0;
        __syncthreads();
        s[t] += v;
        __syncthreads();
    }
    if (t < nblk) row[t] = s[t] - own;              // exclusive
    if (t == 0) tot[blockIdx.x] = s[K_MAX - 1];
}

// ---- pass B2: exclusive scan over bucket totals -> base_e ----
__global__ __launch_bounds__(1024) void k_basescan(
    const int* __restrict__ tot, int* __restrict__ base_e, int K) {
    __shared__ int s[K_MAX];
    int t = threadIdx.x;
    s[t] = (t < K) ? tot[t] : 0;
    __syncthreads();
    for (int off = 1; off < K_MAX; off <<= 1) {
        int v = (t >= off) ? s[t - off] : 0;
        __syncthreads();
        s[t] += v;
        __syncthreads();
    }
    if (t == 0) base_e[0] = 0;
    if (t < K) base_e[t + 1] = s[t];   // base_e[K] == E
}

// ---- pass C: scatter packed edges (src | dst_local<<24) into bucket order ----
__global__ __launch_bounds__(256) void k_scatter(
    const int* __restrict__ src0, const int* __restrict__ dst0,
    const int* __restrict__ cnt, const int* __restrict__ base_e,
    int* __restrict__ packed, int E, int K, int nblk) {
    __shared__ int cur[K_MAX];
    int blk = blockIdx.x;
    for (int b = threadIdx.x; b < K; b += 256)
        cur[b] = base_e[b] + cnt[(size_t)b * nblk + blk];
    __syncthreads();
    int e0 = blk * CH, e1 = min(e0 + CH, E);
    for (int e = e0 + threadIdx.x; e < e1; e += 256) {
        unsigned d = (unsigned)dst0[e];
        int b = d >> LOG_NPB;
        int pos = atomicAdd(&cur[b], 1);
        packed[pos] = src0[e] | ((d & (NPB - 1)) << 24);
    }
}

// ---- degree -> dinv (block per bucket) ----
__global__ __launch_bounds__(1024) void k_deg(
    const int* __restrict__ packed, const int* __restrict__ base_e,
    float* __restrict__ dinv, int N) {
    __shared__ int cnt[NPB];
    int b = blockIdx.x, t = threadIdx.x;
    if (t < NPB) cnt[t] = 0;
    __syncthreads();
    int e0 = base_e[b], e1 = base_e[b + 1];
    for (int e = e0 + t; e < e1; e += 1024)
        atomicAdd(&cnt[(((unsigned)packed[e]) >> 24) & (NPB - 1)], 1);
    __syncthreads();
    if (t < NPB) {
        int node = b * NPB + t;
        if (node < N) dinv[node] = rsqrtf((float)(cnt[t] + 1));  // +1 self-loop
    }
}

// ---- layer 1 GEMM: h1b = bf16((x@W1)*dinv) ----
__global__ __launch_bounds__(256) void k_gemm1(
    const float* __restrict__ x, const float* __restrict__ W1,
    const float* __restrict__ dinv, __hip_bfloat16* __restrict__ h1b, int N) {
    __shared__ float w[F_IN * H1];    // 8 KB
    __shared__ float xt[16 * F_IN];   // 8 KB
    int tid = threadIdx.x;
    int node0 = blockIdx.x * 16;

    const float4* W14 = (const float4*)W1;
    float4* w4 = (float4*)w;
    for (int i = tid; i < F_IN * H1 / 4; i += 256) w4[i] = W14[i];

    const float4* x4 = (const float4*)x;
    float4* xt4 = (float4*)xt;
    for (int i = tid; i < 16 * F_IN / 4; i += 256) {
        int r = i >> 5;
        int node = node0 + r;
        xt4[i] = (node < N) ? x4[(size_t)node * 32 + (i & 31)]
                            : make_float4(0.f, 0.f, 0.f, 0.f);
    }
    __syncthreads();

    int nsub = tid >> 4, f = tid & 15;
    int node = node0 + nsub;
    if (node < N) {
        const float* xr = xt + nsub * F_IN;
        float acc = 0.0f;
        #pragma unroll 16
        for (int k = 0; k < F_IN; ++k)
            acc = fmaf(xr[k], w[k * H1 + f], acc);
        h1b[(size_t)node * H1 + f] = __float2bfloat16(acc * dinv[node]);
    }
}

// ---- layer 1 aggregation: raw sums of h1b[src] into padded LDS, S segs/bucket ----
// 2 threads/edge (16B each), 8 edges in flight per thread.
#define U1 8
__global__ __launch_bounds__(256) void k_agg1(
    const int* __restrict__ packed, const int* __restrict__ base_e,
    const __hip_bfloat16* __restrict__ h1b, float* __restrict__ part1,
    int S) {
    __shared__ float acc[NPB * 17];   // stride 17: odd -> atomics spread all banks
    int bid = blockIdx.x;
    int b = bid / S, seg = bid - b * S;
    int t = threadIdx.x;
    for (int i = t; i < NPB * 17; i += 256) acc[i] = 0.f;
    __syncthreads();

    int e0 = base_e[b], e1 = base_e[b + 1];
    int len = e1 - e0;
    int segLen = (len + S - 1) / S;
    int es = e0 + seg * segLen;
    int ee = min(es + segLen, e1);

    int g = t >> 1, q = t & 1;          // 128 edge-groups, q = feature half
    const uint4* h4 = (const uint4*)h1b;
    for (int e = es + g; e < ee; e += 128 * U1) {
        uint4 v[U1]; int dd[U1]; bool ok[U1];
        #pragma unroll
        for (int u = 0; u < U1; ++u) {
            int eu = e + u * 128;
            ok[u] = eu < ee;
            unsigned p = ok[u] ? (unsigned)packed[eu] : 0u;
            dd[u] = (p >> 24) & (NPB - 1);
            v[u] = h4[(size_t)(p & 0xFFFFFF) * 2 + q];   // p=0 safe
        }
        #pragma unroll
        for (int u = 0; u < U1; ++u) {
            if (ok[u]) {
                float* ap = acc + dd[u] * 17 + q * 8;
                atomicAdd(ap + 0, bflo(v[u].x));
                atomicAdd(ap + 1, bfhi(v[u].x));
                atomicAdd(ap + 2, bflo(v[u].y));
                atomicAdd(ap + 3, bfhi(v[u].y));
                atomicAdd(ap + 4, bflo(v[u].z));
                atomicAdd(ap + 5, bfhi(v[u].z));
                atomicAdd(ap + 6, bflo(v[u].w));
                atomicAdd(ap + 7, bfhi(v[u].w));
            }
        }
    }
    __syncthreads();
    // write [NPB][16] partials (strip pad)
    float4* po = (float4*)(part1 + (size_t)bid * (NPB * H1));
    for (int i = t; i < NPB * H1 / 4; i += 256) {
        int r = i >> 2, c = (i & 3) * 4;
        const float* sp = acc + r * 17 + c;
        po[i] = make_float4(sp[0], sp[1], sp[2], sp[3]);
    }
}

// ---- merge1: (sum partials + self)*dinv, +b1, relu, @W2, pre-scale -> h2s ----
__global__ __launch_bounds__(256) void k_merge1(
    const float* __restrict__ part1, const __hip_bfloat16* __restrict__ h1b,
    const float* __restrict__ dinv, const float* __restrict__ b1,
    const float* __restrict__ W2, float* __restrict__ h2s, int N, int S) {
    int n = blockIdx.x * 256 + threadIdx.x;
    if (n >= N) return;
    int b = n >> LOG_NPB, d = n & (NPB - 1);
    float dv = dinv[n];
    float a[H1];
    const uint4* hh = (const uint4*)h1b;
    uint4 s0 = hh[(size_t)n * 2 + 0];
    uint4 s1 = hh[(size_t)n * 2 + 1];
    a[0] = bflo(s0.x); a[1] = bfhi(s0.x); a[2] = bflo(s0.y); a[3] = bfhi(s0.y);
    a[4] = bflo(s0.z); a[5] = bfhi(s0.z); a[6] = bflo(s0.w); a[7] = bfhi(s0.w);
    a[8] = bflo(s1.x); a[9] = bfhi(s1.x); a[10]= bflo(s1.y); a[11]= bfhi(s1.y);
    a[12]= bflo(s1.z); a[13]= bfhi(s1.z); a[14]= bflo(s1.w); a[15]= bfhi(s1.w);
    for (int s = 0; s < S; ++s) {
        const float4* pp = (const float4*)(part1 + ((size_t)(b * S + s) * NPB + d) * H1);
        #pragma unroll
        for (int qq = 0; qq < 4; ++qq) {
            float4 v = pp[qq];
            a[qq*4+0] += v.x; a[qq*4+1] += v.y;
            a[qq*4+2] += v.z; a[qq*4+3] += v.w;
        }
    }
    float c0 = 0.f, c1 = 0.f;
    #pragma unroll
    for (int f = 0; f < H1; ++f) {
        float v = fmaxf(fmaf(a[f], dv, b1[f]), 0.f);
        c0 = fmaf(v, W2[f * C_OUT + 0], c0);
        c1 = fmaf(v, W2[f * C_OUT + 1], c1);
    }
    ((float2*)h2s)[n] = make_float2(c0 * dv, c1 * dv);
}

// ---- layer 2 aggregation: raw sums of h2s[src], S segs/bucket ----
#define U2 8
__global__ __launch_bounds__(256) void k_agg2(
    const int* __restrict__ packed, const int* __restrict__ base_e,
    const float* __restrict__ h2s, float* __restrict__ part2, int S) {
    __shared__ float acc[NPB * 3];   // stride 3
    int bid = blockIdx.x;
    int b = bid / S, seg = bid - b * S;
    int t = threadIdx.x;
    for (int i = t; i < NPB * 3; i += 256) acc[i] = 0.f;
    __syncthreads();

    int e0 = base_e[b], e1 = base_e[b + 1];
    int len = e1 - e0;
    int segLen = (len + S - 1) / S;
    int es = e0 + seg * segLen;
    int ee = min(es + segLen, e1);

    const float2* h2 = (const float2*)h2s;
    for (int e = es + t; e < ee; e += 256 * U2) {
        float2 v[U2]; int dd[U2]; bool ok[U2];
        #pragma unroll
        for (int u = 0; u < U2; ++u) {
            int eu = e + u * 256;
            ok[u] = eu < ee;
            unsigned p = ok[u] ? (unsigned)packed[eu] : 0u;
            dd[u] = (p >> 24) & (NPB - 1);
            v[u] = h2[p & 0xFFFFFF];
        }
        #pragma unroll
        for (int u = 0; u < U2; ++u) {
            if (ok[u]) {
                atomicAdd(&acc[dd[u] * 3 + 0], v[u].x);
                atomicAdd(&acc[dd[u] * 3 + 1], v[u].y);
            }
        }
    }
    __syncthreads();
    float2* po = (float2*)(part2 + (size_t)bid * (NPB * 2));
    for (int i = t; i < NPB; i += 256)
        po[i] = make_float2(acc[i * 3 + 0], acc[i * 3 + 1]);
}

// ---- merge2: (sum partials + self)*dinv + b2, log_softmax -> out ----
__global__ __launch_bounds__(256) void k_merge2(
    const float* __restrict__ part2, const float* __restrict__ h2s,
    const float* __restrict__ dinv, const float* __restrict__ b2,
    float* __restrict__ out, int N, int S) {
    int n = blockIdx.x * 256 + threadIdx.x;
    if (n >= N) return;
    int b = n >> LOG_NPB, d = n & (NPB - 1);
    float dv = dinv[n];
    float2 h = ((const float2*)h2s)[n];
    float a0 = h.x, a1 = h.y;
    for (int s = 0; s < S; ++s) {
        float2 v = ((const float2*)part2)[(size_t)(b * S + s) * NPB + d];
        a0 += v.x; a1 += v.y;
    }
    a0 = fmaf(a0, dv, b2[0]);
    a1 = fmaf(a1, dv, b2[1]);
    float m = fmaxf(a0, a1);
    float lse = m + logf(expf(a0 - m) + expf(a1 - m));
    ((float2*)out)[n] = make_float2(a0 - lse, a1 - lse);
}

extern "C" void kernel_launch(void* const* d_in, const int* in_sizes, int n_in,
                              void* d_out, int out_size, void* d_ws, size_t ws_size,
                              hipStream_t stream) {
    const float* x  = (const float*)d_in[0];
    const int* ei   = (const int*)d_in[1];
    const float* W1 = (const float*)d_in[2];
    const float* b1 = (const float*)d_in[3];
    const float* W2 = (const float*)d_in[4];
    const float* b2 = (const float*)d_in[5];
    float* out = (float*)d_out;

    const int N = in_sizes[0] / F_IN;     // 100000
    const int E = in_sizes[1] / 2;        // 3200000
    const int* src0 = ei;
    const int* dst0 = ei + E;

    const int K = (N + NPB - 1) >> LOG_NPB;      // 782
    const int nblk = (E + CH - 1) / CH;          // 782

    // adaptive segment count based on ws capacity
    size_t fixed_f = (size_t)N * (1 + H1 / 2 + C_OUT) + (size_t)E
                   + (size_t)K * nblk + K + (K + 1) + 32;
    size_t perS_f = (size_t)K * (NPB * H1 + NPB * C_OUT);
    size_t avail_f = ws_size / 4;
    int S = 4;
    while (S > 1 && fixed_f + (size_t)S * perS_f > avail_f) S >>= 1;

    // workspace layout (float units), 16B-aligned chunks
    size_t off = 0;
    float* wsf = (float*)d_ws;
    auto take = [&](size_t nf) { float* p = wsf + off; off += (nf + 3) & ~(size_t)3; return p; };
    float* dinv   = take(N);
    __hip_bfloat16* h1b = (__hip_bfloat16*)take((size_t)N * H1 / 2);
    float* h2s    = take((size_t)N * C_OUT);
    int*   packed = (int*)take(E);
    int*   cnt    = (int*)take((size_t)K * nblk);
    int*   tot    = (int*)take(K);
    int*   base_e = (int*)take(K + 1);
    float* part1  = take((size_t)K * S * NPB * H1);
    float* part2  = take((size_t)K * S * NPB * C_OUT);

    int nbN = (N + 255) / 256;

    k_part_count<<<nblk, 256, 0, stream>>>(dst0, cnt, E, K, nblk);
    k_colscan<<<K, 1024, 0, stream>>>(cnt, tot, nblk);
    k_basescan<<<1, 1024, 0, stream>>>(tot, base_e, K);
    k_scatter<<<nblk, 256, 0, stream>>>(src0, dst0, cnt, base_e, packed, E, K, nblk);
    k_deg<<<K, 1024, 0, stream>>>(packed, base_e, dinv, N);
    k_gemm1<<<(N + 15) / 16, 256, 0, stream>>>(x, W1, dinv, h1b, N);
    k_agg1<<<K * S, 256, 0, stream>>>(packed, base_e, h1b, part1, S);
    k_merge1<<<nbN, 256, 0, stream>>>(part1, h1b, dinv, b1, W2, h2s, N, S);
    k_agg2<<<K * S, 256, 0, stream>>>(packed, base_e, h2s, part2, S);
    k_merge2<<<nbN, 256, 0, stream>>>(part2, h2s, dinv, b2, out, N, S);
}